// Round 1
// baseline (971.836 us; speedup 1.0000x reference)
//
#include <hip/hip_runtime.h>
#include <cstdint>
#include <cstddef>

// ---------------------------------------------------------------------------
// Problem constants
//   B=2048, INPUT_DIM=HIDDEN=128, OUT=64, HYPER_H=1024, TOTAL_PARAMS=57792
//   flat col layout: [L1 W 0..16384) [L1 b 16384..16512) [L2 W 16512..32896)
//                    [L2 b 32896..33024) [L3 W 33024..49408) [L3 b 49408..49536)
//                    [L4 W 49536..57728) [L4 b 57728..57792)
// ---------------------------------------------------------------------------

typedef __attribute__((ext_vector_type(8))) short short8;
typedef __attribute__((ext_vector_type(4))) float f32x4;

__device__ __forceinline__ unsigned short f2bf(float f) {
  union { float f; uint32_t u; } c; c.f = f;
  uint32_t u = c.u;
  return (unsigned short)((u + 0x7FFFu + ((u >> 16) & 1u)) >> 16);  // RNE
}
__device__ __forceinline__ float bf2f(unsigned short b) {
  union { uint32_t u; float f; } c; c.u = ((uint32_t)b) << 16;
  return c.f;
}
// tb column j (0..447) -> flat column (bias ranges)
__device__ __forceinline__ int mapbias(int j) {
  if (j < 128) return 16384 + j;      // L1 bias
  if (j < 256) return 32768 + j;      // 32896 + (j-128)
  if (j < 384) return 49152 + j;      // 49408 + (j-256)
  return 57344 + j;                   // 57728 + (j-384)
}
// XCD-aware bijective block swizzle (requires gridDim.x*gridDim.y % 8 == 0)
__device__ __forceinline__ void swz_block(int& bx, int& by) {
  int gx = gridDim.x;
  int n = gx * gridDim.y;
  int f = by * gx + bx;
  int per = n >> 3;
  int s = (f & 7) * per + (f >> 3);
  bx = s % gx; by = s / gx;
}

// ---------------------------------------------------------------------------
// prep: x (2048x128 f32) -> bf16
// ---------------------------------------------------------------------------
__global__ void prep_x(const float* __restrict__ x, unsigned short* __restrict__ xbf) {
  int i = (blockIdx.x * 256 + threadIdx.x) * 4;
  float4 v = *(const float4*)(x + i);
  unsigned short o0 = f2bf(v.x), o1 = f2bf(v.y), o2 = f2bf(v.z), o3 = f2bf(v.w);
  ushort4 o; o.x = o0; o.y = o1; o.z = o2; o.w = o3;
  *(ushort4*)(xbf + i) = o;
}

// ---------------------------------------------------------------------------
// hyper layer 1: h1 = relu(ow @ W1 + b1) -> bf16   (K=3, trivial)
// ---------------------------------------------------------------------------
__global__ void hyper1_k(const float* __restrict__ ow, const float* __restrict__ W1,
                         const float* __restrict__ b1, unsigned short* __restrict__ h1bf) {
  int idx = blockIdx.x * 256 + threadIdx.x;   // 2048*1024 total
  int b = idx >> 10, j = idx & 1023;
  float s = b1[j] + ow[b * 3 + 0] * W1[j]
                  + ow[b * 3 + 1] * W1[1024 + j]
                  + ow[b * 3 + 2] * W1[2048 + j];
  h1bf[idx] = f2bf(fmaxf(s, 0.f));
}

// ---------------------------------------------------------------------------
// Generic small MFMA GEMM: Out = act(A_bf16 @ bf16(Bsrc_f32[:,colmap]) + bias)
// Tile: BM=64, BN=64, BK=32. 256 threads / 4 waves, wave w owns cols w*16..+16.
// CMAP 0: col identity (bias[col]); CMAP 1: bias-range map (bias[mapbias(col)]).
// ---------------------------------------------------------------------------
template <int CMAP, bool RELU, bool OUTBF>
__global__ __launch_bounds__(256, 2)
void gemm_small(const unsigned short* __restrict__ A, const float* __restrict__ Bsrc,
                const float* __restrict__ bias, void* __restrict__ Out,
                int lda, int ldb, int ldo, int K) {
  __shared__ __align__(16) char smem[8192];
  char* As = smem;          // [64 rows][64B], chunk-XOR-swizzled
  char* Bs = smem + 4096;   // [4 kgrp][64 n][16B]
  int bx = blockIdx.x, by = blockIdx.y;
  swz_block(bx, by);
  int t = threadIdx.x, lane = t & 63, w = t >> 6;
  int lo = lane & 15, hi = lane >> 4;
  int bbase = bx * 64, nbase = by * 64;

  int bn = t & 63, bp = t >> 6;
  int bj = nbase + bn;
  int bcol = (CMAP == 0) ? bj : mapbias(bj);
  int ar = t >> 2, ach = t & 3;

  f32x4 acc[4] = {};

  for (int kb = 0; kb < K; kb += 32) {
    // stage A (64x32 bf16)
    uint4 av = *(const uint4*)(A + (size_t)(bbase + ar) * lda + kb + ach * 8);
    *(uint4*)(As + ar * 64 + ((ach ^ (ar & 3)) << 4)) = av;
    // stage B: 8 strided f32 loads along k for this thread's column
    float fb[8];
    const float* src = Bsrc + (size_t)(kb + bp * 8) * ldb + bcol;
#pragma unroll
    for (int j = 0; j < 8; j++) fb[j] = src[(size_t)j * ldb];
    uint4 wv;
    wv.x = f2bf(fb[0]) | ((uint32_t)f2bf(fb[1]) << 16);
    wv.y = f2bf(fb[2]) | ((uint32_t)f2bf(fb[3]) << 16);
    wv.z = f2bf(fb[4]) | ((uint32_t)f2bf(fb[5]) << 16);
    wv.w = f2bf(fb[6]) | ((uint32_t)f2bf(fb[7]) << 16);
    *(uint4*)(Bs + bp * 1024 + bn * 16) = wv;
    __syncthreads();

    short8 af[4];
#pragma unroll
    for (int m = 0; m < 4; m++) {
      int row = m * 16 + lo;
      af[m] = *(const short8*)(As + row * 64 + ((hi ^ (row & 3)) << 4));
    }
    short8 bv = *(const short8*)(Bs + hi * 1024 + (w * 16 + lo) * 16);
#pragma unroll
    for (int m = 0; m < 4; m++)
      acc[m] = __builtin_amdgcn_mfma_f32_16x16x32_bf16(af[m], bv, acc[m], 0, 0, 0);
    __syncthreads();
  }

  int col = nbase + w * 16 + lo;
  int mc = (CMAP == 0) ? col : mapbias(col);
  float bvadd = bias[mc];
#pragma unroll
  for (int m = 0; m < 4; m++) {
#pragma unroll
    for (int r = 0; r < 4; r++) {
      int row = bbase + m * 16 + hi * 4 + r;
      float v = acc[m][r] + bvadd;
      if (RELU) v = fmaxf(v, 0.f);
      if (OUTBF) ((unsigned short*)Out)[(size_t)row * ldo + col] = f2bf(v);
      else       ((float*)Out)[(size_t)row * ldo + col] = v;
    }
  }
}

// ---------------------------------------------------------------------------
// Fused target layer:
//   P[b, c] = sum_k h2[b,k]*W3[k, Woff+c] (+ b3[Woff+c]),  c = o_local*128 + i
//   y[b,o]  = act( sum_i P[b, o*128+i]*xin[b,i] + tb[b, tbBase+o] )
// WG: 128 samples x 4 outputs (512 flat cols). 512 thr / 8 waves (2M x 4O).
// Each wave: M=64 rows, one output o, N=128 cols, acc 4x8 frags.
// ---------------------------------------------------------------------------
template <bool RELU, bool OUTF32>
__global__ __launch_bounds__(512, 2)
void layer_fused(const unsigned short* __restrict__ h2bf, const float* __restrict__ W3,
                 const float* __restrict__ b3, const unsigned short* __restrict__ xin,
                 const float* __restrict__ tb, int tbBase, void* __restrict__ Out,
                 int Woff) {
  __shared__ __align__(16) char smem[40960];
  char* As = smem;          // 8KB  [128 rows][64B] chunk-XOR-swizzled
  char* Bs = smem + 8192;   // 32KB [4 kgrp][512 n][16B]; reused for X in epilogue
  int bx = blockIdx.x, by = blockIdx.y;
  swz_block(bx, by);
  int t = threadIdx.x, lane = t & 63, w = t >> 6;
  int lo = lane & 15, hi = lane >> 4;
  int wm = w >> 2, wo = w & 3;
  int bbase = bx * 128;
  int obase = by * 4;
  int o = obase + wo;
  int colstart = Woff + obase * 128;   // this WG's 512 flat cols
  int ar = t >> 2, ach = t & 3;
  const float* bcol0 = W3 + colstart + t;  // thread's column

  f32x4 acc[4][8] = {};

  for (int kb = 0; kb < 1024; kb += 32) {
    // stage A (128x32 bf16 from h2bf)
    uint4 av = *(const uint4*)(h2bf + (size_t)(bbase + ar) * 1024 + kb + ach * 8);
    *(uint4*)(As + ar * 64 + ((ach ^ (ar & 3)) << 4)) = av;
    // stage B: 32 strided f32 loads (k-walk) for this thread's column, in 2 halves
#pragma unroll
    for (int p = 0; p < 2; p++) {
      float fb[16];
      const float* src = bcol0 + (size_t)(kb + p * 16) * 57792;
#pragma unroll
      for (int j = 0; j < 16; j++) fb[j] = src[(size_t)j * 57792];
#pragma unroll
      for (int q = 0; q < 2; q++) {
        uint4 wv;
        wv.x = f2bf(fb[q * 8 + 0]) | ((uint32_t)f2bf(fb[q * 8 + 1]) << 16);
        wv.y = f2bf(fb[q * 8 + 2]) | ((uint32_t)f2bf(fb[q * 8 + 3]) << 16);
        wv.z = f2bf(fb[q * 8 + 4]) | ((uint32_t)f2bf(fb[q * 8 + 5]) << 16);
        wv.w = f2bf(fb[q * 8 + 6]) | ((uint32_t)f2bf(fb[q * 8 + 7]) << 16);
        *(uint4*)(Bs + (p * 2 + q) * 8192 + t * 16) = wv;
      }
    }
    __syncthreads();

    short8 af[4];
#pragma unroll
    for (int m = 0; m < 4; m++) {
      int row = wm * 64 + m * 16 + lo;
      af[m] = *(const short8*)(As + row * 64 + ((hi ^ (row & 3)) << 4));
    }
#pragma unroll
    for (int nf = 0; nf < 8; nf++) {
      short8 bv = *(const short8*)(Bs + hi * 8192 + (wo * 128 + nf * 16 + lo) * 16);
#pragma unroll
      for (int m = 0; m < 4; m++)
        acc[m][nf] = __builtin_amdgcn_mfma_f32_16x16x32_bf16(af[m], bv, acc[m][nf], 0, 0, 0);
    }
    __syncthreads();
  }

  // stage xin tile (128x128 bf16 = 32KB) into Bs
#pragma unroll
  for (int pass = 0; pass < 4; pass++) {
    int idx = pass * 512 + t;
    int row = idx >> 4, ch = idx & 15;
    uint4 v = *(const uint4*)(xin + (size_t)(bbase + row) * 128 + ch * 8);
    *(uint4*)(Bs + row * 256 + ch * 16) = v;
  }
  __syncthreads();
  const unsigned short* Xs = (const unsigned short*)Bs;

  // b3 contribution for this lane's 8 columns (i = nf*16+lo)
  float b3g[8];
#pragma unroll
  for (int nf = 0; nf < 8; nf++) b3g[nf] = b3[colstart + wo * 128 + nf * 16 + lo];

  float osum[4][4] = {};
#pragma unroll
  for (int m = 0; m < 4; m++) {
#pragma unroll
    for (int r = 0; r < 4; r++) {
      int brow = wm * 64 + m * 16 + hi * 4 + r;
      float s = 0.f;
#pragma unroll
      for (int nf = 0; nf < 8; nf++) {
        float xv = bf2f(Xs[brow * 128 + nf * 16 + lo]);
        s += (acc[m][nf][r] + b3g[nf]) * xv;
      }
      osum[m][r] = s;
    }
  }
#pragma unroll
  for (int m = 0; m < 4; m++) {
#pragma unroll
    for (int r = 0; r < 4; r++) {
      float v = osum[m][r];
      v += __shfl_xor(v, 1);
      v += __shfl_xor(v, 2);
      v += __shfl_xor(v, 4);
      v += __shfl_xor(v, 8);
      if (lo == 0) {
        int brow = wm * 64 + m * 16 + hi * 4 + r;
        int gb = bbase + brow;
        float y = v + tb[(size_t)gb * 448 + tbBase + o];
        if (RELU) y = fmaxf(y, 0.f);
        if (OUTF32) ((float*)Out)[(size_t)gb * 64 + o] = y;
        else        ((unsigned short*)Out)[(size_t)gb * 128 + o] = f2bf(y);
      }
    }
  }
}

// ---------------------------------------------------------------------------
// softmax over 64 cols; one wave per row
// ---------------------------------------------------------------------------
__global__ void softmax_k(const float* __restrict__ logits, float* __restrict__ out) {
  int t = threadIdx.x, w = t >> 6, lane = t & 63;
  int row = blockIdx.x * 4 + w;
  float v = logits[row * 64 + lane];
  float m = v;
  m = fmaxf(m, __shfl_xor(m, 1));
  m = fmaxf(m, __shfl_xor(m, 2));
  m = fmaxf(m, __shfl_xor(m, 4));
  m = fmaxf(m, __shfl_xor(m, 8));
  m = fmaxf(m, __shfl_xor(m, 16));
  m = fmaxf(m, __shfl_xor(m, 32));
  float e = expf(v - m);
  float s = e;
  s += __shfl_xor(s, 1);
  s += __shfl_xor(s, 2);
  s += __shfl_xor(s, 4);
  s += __shfl_xor(s, 8);
  s += __shfl_xor(s, 16);
  s += __shfl_xor(s, 32);
  out[row * 64 + lane] = e / s;
}

// ---------------------------------------------------------------------------
extern "C" void kernel_launch(void* const* d_in, const int* in_sizes, int n_in,
                              void* d_out, int out_size, void* d_ws, size_t ws_size,
                              hipStream_t stream) {
  (void)in_sizes; (void)n_in; (void)out_size; (void)ws_size;
  const float* x  = (const float*)d_in[0];
  const float* ow = (const float*)d_in[1];
  const float* W1 = (const float*)d_in[2];
  const float* b1 = (const float*)d_in[3];
  const float* W2 = (const float*)d_in[4];
  const float* b2 = (const float*)d_in[5];
  const float* W3 = (const float*)d_in[6];
  const float* b3 = (const float*)d_in[7];

  char* ws = (char*)d_ws;
  unsigned short* xbf  = (unsigned short*)(ws + 0);          // 2048x128 bf16
  unsigned short* h1bf = (unsigned short*)(ws + 524288);     // 2048x1024 bf16
  unsigned short* h2bf = (unsigned short*)(ws + 4718592);    // 2048x1024 bf16
  float*          tb   = (float*)(ws + 8912896);             // 2048x448 f32
  unsigned short* ht1  = (unsigned short*)(ws + 12582912);   // 2048x128 bf16
  unsigned short* ht2  = (unsigned short*)(ws + 13107200);
  unsigned short* ht3  = (unsigned short*)(ws + 13631488);
  float*       logits  = (float*)(ws + 14155776);            // 2048x64 f32
  float* out = (float*)d_out;

  prep_x<<<256, 256, 0, stream>>>(x, xbf);
  hyper1_k<<<8192, 256, 0, stream>>>(ow, W1, b1, h1bf);
  // h2 = relu(h1 @ W2 + b2)                M=2048 N=1024 K=1024
  gemm_small<0, true, true><<<dim3(32, 16), 256, 0, stream>>>(h1bf, W2, b2, h2bf, 1024, 1024, 1024, 1024);
  // target biases: tb[b, j] = h2 . W3[:, mapbias(j)] + b3[mapbias(j)]   N=448
  gemm_small<1, false, false><<<dim3(32, 7), 256, 0, stream>>>(h2bf, W3, b3, tb, 1024, 57792, 448, 1024);
  // fused target layers
  layer_fused<true,  false><<<dim3(16, 32), 512, 0, stream>>>(h2bf, W3, b3, xbf, tb, 0,   ht1, 0);
  layer_fused<true,  false><<<dim3(16, 32), 512, 0, stream>>>(h2bf, W3, b3, ht1, tb, 128, ht2, 16512);
  layer_fused<true,  false><<<dim3(16, 32), 512, 0, stream>>>(h2bf, W3, b3, ht2, tb, 256, ht3, 33024);
  layer_fused<false, true ><<<dim3(16, 16), 512, 0, stream>>>(h2bf, W3, b3, ht3, tb, 384, logits, 49536);
  softmax_k<<<512, 256, 0, stream>>>(logits, out);
}

// Round 4
// 621.556 us; speedup vs baseline: 1.5636x; 1.5636x over previous
//
#include <hip/hip_runtime.h>
#include <cstdint>
#include <cstddef>

// ---------------------------------------------------------------------------
// Problem constants
//   B=2048, INPUT_DIM=HIDDEN=128, OUT=64, HYPER_H=1024, TOTAL_PARAMS=57792
//   flat col layout: [L1 W 0..16384) [L1 b 16384..16512) [L2 W 16512..32896)
//                    [L2 b 32896..33024) [L3 W 33024..49408) [L3 b 49408..49536)
//                    [L4 W 49536..57728) [L4 b 57728..57792)
// ---------------------------------------------------------------------------

typedef __attribute__((ext_vector_type(8))) short short8;
typedef __attribute__((ext_vector_type(4))) float f32x4;

__device__ __forceinline__ unsigned short f2bf(float f) {
  union { float f; uint32_t u; } c; c.f = f;
  uint32_t u = c.u;
  return (unsigned short)((u + 0x7FFFu + ((u >> 16) & 1u)) >> 16);  // RNE
}
__device__ __forceinline__ float bf2f(unsigned short b) {
  union { uint32_t u; float f; } c; c.u = ((uint32_t)b) << 16;
  return c.f;
}
// tb column j (0..447) -> flat column (bias ranges)
__device__ __forceinline__ int mapbias(int j) {
  if (j < 128) return 16384 + j;
  if (j < 256) return 32768 + j;
  if (j < 384) return 49152 + j;
  return 57344 + j;
}
// XCD-aware bijective block swizzle (requires gridDim.x*gridDim.y % 8 == 0)
__device__ __forceinline__ void swz_block(int& bx, int& by) {
  int gx = gridDim.x;
  int n = gx * gridDim.y;
  int f = by * gx + bx;
  int per = n >> 3;
  int s = (f & 7) * per + (f >> 3);
  bx = s % gx; by = s / gx;
}
// async global->LDS 16B; dest must be wave-uniform base + lane*16 (linear in t)
__device__ __forceinline__ void gl_lds16(const void* g, void* l) {
  __builtin_amdgcn_global_load_lds(
      (const __attribute__((address_space(1))) void*)g,
      (__attribute__((address_space(3))) void*)l, 16, 0, 0);
}

// ---------------------------------------------------------------------------
// prep: x (2048x128 f32) -> bf16
// ---------------------------------------------------------------------------
__global__ void prep_x(const float* __restrict__ x, unsigned short* __restrict__ xbf) {
  int i = (blockIdx.x * 256 + threadIdx.x) * 4;
  float4 v = *(const float4*)(x + i);
  ushort4 o; o.x = f2bf(v.x); o.y = f2bf(v.y); o.z = f2bf(v.z); o.w = f2bf(v.w);
  *(ushort4*)(xbf + i) = o;
}

// ---------------------------------------------------------------------------
// hyper layer 1: h1 = relu(ow @ W1 + b1) -> bf16   (K=3, trivial)
// ---------------------------------------------------------------------------
__global__ void hyper1_k(const float* __restrict__ ow, const float* __restrict__ W1,
                         const float* __restrict__ b1, unsigned short* __restrict__ h1bf) {
  int idx = blockIdx.x * 256 + threadIdx.x;
  int b = idx >> 10, j = idx & 1023;
  float s = b1[j] + ow[b * 3 + 0] * W1[j]
                  + ow[b * 3 + 1] * W1[1024 + j]
                  + ow[b * 3 + 2] * W1[2048 + j];
  h1bf[idx] = f2bf(fmaxf(s, 0.f));
}

// ---------------------------------------------------------------------------
// pack fp32 [K][N] -> bf16 blocked [(K/32)*4 + kgrp][c][8k]  (one 16B chunk per
// thread; reads coalesced across c, writes contiguous). grid = K*N/8/256.
// ---------------------------------------------------------------------------
__global__ void pack_b(const float* __restrict__ src, unsigned short* __restrict__ dst, int N) {
  int idx = blockIdx.x * 256 + threadIdx.x;     // chunk index = g*N + c
  int c = idx % N;
  int g = idx / N;
  int k0 = (g >> 2) * 32 + (g & 3) * 8;
  const float* s = src + (size_t)k0 * N + c;
  uint4 wv;
  wv.x = f2bf(s[0])            | ((uint32_t)f2bf(s[(size_t)N])     << 16);
  wv.y = f2bf(s[2 * (size_t)N]) | ((uint32_t)f2bf(s[3 * (size_t)N]) << 16);
  wv.z = f2bf(s[4 * (size_t)N]) | ((uint32_t)f2bf(s[5 * (size_t)N]) << 16);
  wv.w = f2bf(s[6 * (size_t)N]) | ((uint32_t)f2bf(s[7 * (size_t)N]) << 16);
  *(uint4*)(dst + (size_t)idx * 8) = wv;
}

// ---------------------------------------------------------------------------
// PACKED small GEMM: Out = act(A_bf16 @ BPacked + bias). BM=64 BN=64 BK=32.
// 256 thr / 4 waves; wave w owns cols w*16..+16. All staging via global_load_lds.
// A-LDS: [64 rows][4 chunks], swizzle pos = ch ^ ((row>>1)&3)  (2-way = free).
// ---------------------------------------------------------------------------
template <int CMAP, bool RELU, bool OUTBF>
__global__ __launch_bounds__(256, 4)
void gemm_packed(const unsigned short* __restrict__ A, const unsigned short* __restrict__ BP,
                 const float* __restrict__ bias, void* __restrict__ Out,
                 int lda, int ldbp, int ldo, int K) {
  __shared__ __align__(16) char smem[8192];
  char* As = smem;          // 4 KB
  char* Bs = smem + 4096;   // 4 KB: [4 kgrp][64 c][16B]
  int bx = blockIdx.x, by = blockIdx.y;
  swz_block(bx, by);
  int t = threadIdx.x, lane = t & 63, w = t >> 6;
  int lo = lane & 15, hi = lane >> 4;
  int bbase = bx * 64, nbase = by * 64;
  int ar = t >> 2, ach = t & 3;
  int bkg = t >> 6, bc = t & 63;
  int bj = nbase + bc;
  int bcol = (CMAP == 0) ? bj : mapbias(bj);

  f32x4 acc[4] = {};

  for (int kb = 0; kb < K; kb += 32) {
    gl_lds16(A + (size_t)(bbase + ar) * lda + kb + ((ach ^ ((ar >> 1) & 3)) << 3),
             As + t * 16);
    gl_lds16(BP + ((size_t)((kb >> 5) * 4 + bkg) * ldbp + bcol) * 8, Bs + t * 16);
    __syncthreads();
    short8 af[4];
#pragma unroll
    for (int m = 0; m < 4; m++) {
      int row = m * 16 + lo;
      af[m] = *(const short8*)(As + row * 64 + ((hi ^ ((row >> 1) & 3)) << 4));
    }
    short8 bv = *(const short8*)(Bs + (hi * 64 + w * 16 + lo) * 16);
#pragma unroll
    for (int m = 0; m < 4; m++)
      acc[m] = __builtin_amdgcn_mfma_f32_16x16x32_bf16(af[m], bv, acc[m], 0, 0, 0);
    __syncthreads();
  }

  int col = nbase + w * 16 + lo;
  int mc = (CMAP == 0) ? col : mapbias(col);
  float bvadd = bias[mc];
#pragma unroll
  for (int m = 0; m < 4; m++) {
#pragma unroll
    for (int r = 0; r < 4; r++) {
      int row = bbase + m * 16 + hi * 4 + r;
      float v = acc[m][r] + bvadd;
      if (RELU) v = fmaxf(v, 0.f);
      if (OUTBF) ((unsigned short*)Out)[(size_t)row * ldo + col] = f2bf(v);
      else       ((float*)Out)[(size_t)row * ldo + col] = v;
    }
  }
}

// ---------------------------------------------------------------------------
// PACKED fused target layer. WG = 128 samples x 2 outputs (256 flat cols).
// 512 thr / 8 waves = 4M x 2O; wave: 32 rows x 128 cols -> acc[2][8] (64 VGPR).
// BK=64. A-LDS 16 KB [128 rows][8 chunks] pos = ch ^ (row&7) (2-way = free);
// B-LDS 32 KB [8 kgrp][256 c][16B]. All staging global_load_lds (linear dest,
// inverse-swizzled source). X tile (32 KB) overlays smem in epilogue.
// ---------------------------------------------------------------------------
template <bool RELU, bool OUTF32>
__global__ __launch_bounds__(512, 4)
void layer_packed(const unsigned short* __restrict__ h2bf,
                  const unsigned short* __restrict__ W3S,
                  const float* __restrict__ b3,
                  const unsigned short* __restrict__ xin,
                  const float* __restrict__ tb, int tbBase,
                  void* __restrict__ Out, int Woff) {
  __shared__ __align__(16) char smem[49152];
  char* As = smem;           // 16 KB
  char* Bs = smem + 16384;   // 32 KB
  int bx = blockIdx.x, by = blockIdx.y;
  swz_block(bx, by);
  int t = threadIdx.x, lane = t & 63, w = t >> 6;
  int lo = lane & 15, hi = lane >> 4;
  int wm = w >> 1, wo = w & 1;
  int bbase = bx * 128;
  int obase = by * 2;
  int colstart = Woff + obase * 128;   // this WG's 256 flat cols

  f32x4 acc[2][8] = {};

  for (int kb = 0; kb < 1024; kb += 64) {
    // A stage: 16 KB, 2 rounds. idx=(ar,ach): src chunk = ach ^ (ar&7)
#pragma unroll
    for (int r = 0; r < 2; r++) {
      int idx = r * 512 + t;
      int ar = idx >> 3, ach = idx & 7;
      gl_lds16(h2bf + (size_t)(bbase + ar) * 1024 + kb + ((ach ^ (ar & 7)) << 3),
               As + idx * 16);
    }
    // B stage: 32 KB, 4 rounds. idx=(kgrp,c); packed groups are k-contiguous
    const unsigned short* bsrc = W3S + ((size_t)(kb >> 5) * 4 * 57792 + colstart) * 8;
#pragma unroll
    for (int r = 0; r < 4; r++) {
      int idx = r * 512 + t;
      int kgrp = idx >> 8, c = idx & 255;
      gl_lds16(bsrc + ((size_t)kgrp * 57792 + c) * 8, Bs + idx * 16);
    }
    __syncthreads();
#pragma unroll
    for (int s = 0; s < 2; s++) {
      short8 af[2];
#pragma unroll
      for (int m = 0; m < 2; m++) {
        int row = wm * 32 + m * 16 + lo;
        int pos = (s * 4 + hi) ^ (row & 7);
        af[m] = *(const short8*)(As + row * 128 + (pos << 4));
      }
#pragma unroll
      for (int nf = 0; nf < 8; nf++) {
        short8 bv = *(const short8*)(Bs + (((s * 4 + hi) * 256) + wo * 128 + nf * 16 + lo) * 16);
        acc[0][nf] = __builtin_amdgcn_mfma_f32_16x16x32_bf16(af[0], bv, acc[0][nf], 0, 0, 0);
        acc[1][nf] = __builtin_amdgcn_mfma_f32_16x16x32_bf16(af[1], bv, acc[1][nf], 0, 0, 0);
      }
    }
    __syncthreads();
  }

  // stage xin tile (128x128 bf16 = 32 KB) over smem
#pragma unroll
  for (int r = 0; r < 4; r++) {
    int idx = r * 512 + t;
    int row = idx >> 4, ch = idx & 15;
    gl_lds16(xin + (size_t)(bbase + row) * 128 + ch * 8, smem + idx * 16);
  }
  __syncthreads();
  const unsigned short* Xs = (const unsigned short*)smem;

  int o = obase + wo;
  float b3g[8];
#pragma unroll
  for (int nf = 0; nf < 8; nf++) b3g[nf] = b3[colstart + wo * 128 + nf * 16 + lo];

#pragma unroll
  for (int m = 0; m < 2; m++) {
#pragma unroll
    for (int r = 0; r < 4; r++) {
      int brow = wm * 32 + m * 16 + hi * 4 + r;
      float s = 0.f;
#pragma unroll
      for (int nf = 0; nf < 8; nf++) {
        float xv = bf2f(Xs[brow * 128 + nf * 16 + lo]);
        s += (acc[m][nf][r] + b3g[nf]) * xv;
      }
      s += __shfl_xor(s, 1);
      s += __shfl_xor(s, 2);
      s += __shfl_xor(s, 4);
      s += __shfl_xor(s, 8);
      if (lo == 0) {
        int gb = bbase + brow;
        float y = s + tb[(size_t)gb * 448 + tbBase + o];
        if (RELU) y = fmaxf(y, 0.f);
        if (OUTF32) ((float*)Out)[(size_t)gb * 64 + o] = y;
        else        ((unsigned short*)Out)[(size_t)gb * 128 + o] = f2bf(y);
      }
    }
  }
}

// ---------------------------------------------------------------------------
// FALLBACK path (round-1 kernels, used when ws_size can't hold packed W3)
// ---------------------------------------------------------------------------
template <int CMAP, bool RELU, bool OUTBF>
__global__ __launch_bounds__(256, 2)
void gemm_small(const unsigned short* __restrict__ A, const float* __restrict__ Bsrc,
                const float* __restrict__ bias, void* __restrict__ Out,
                int lda, int ldb, int ldo, int K) {
  __shared__ __align__(16) char smem[8192];
  char* As = smem;
  char* Bs = smem + 4096;
  int bx = blockIdx.x, by = blockIdx.y;
  swz_block(bx, by);
  int t = threadIdx.x, lane = t & 63, w = t >> 6;
  int lo = lane & 15, hi = lane >> 4;
  int bbase = bx * 64, nbase = by * 64;
  int bn = t & 63, bp = t >> 6;
  int bj = nbase + bn;
  int bcol = (CMAP == 0) ? bj : mapbias(bj);
  int ar = t >> 2, ach = t & 3;
  f32x4 acc[4] = {};
  for (int kb = 0; kb < K; kb += 32) {
    uint4 av = *(const uint4*)(A + (size_t)(bbase + ar) * lda + kb + ach * 8);
    *(uint4*)(As + ar * 64 + ((ach ^ (ar & 3)) << 4)) = av;
    float fb[8];
    const float* src = Bsrc + (size_t)(kb + bp * 8) * ldb + bcol;
#pragma unroll
    for (int j = 0; j < 8; j++) fb[j] = src[(size_t)j * ldb];
    uint4 wv;
    wv.x = f2bf(fb[0]) | ((uint32_t)f2bf(fb[1]) << 16);
    wv.y = f2bf(fb[2]) | ((uint32_t)f2bf(fb[3]) << 16);
    wv.z = f2bf(fb[4]) | ((uint32_t)f2bf(fb[5]) << 16);
    wv.w = f2bf(fb[6]) | ((uint32_t)f2bf(fb[7]) << 16);
    *(uint4*)(Bs + bp * 1024 + bn * 16) = wv;
    __syncthreads();
    short8 af[4];
#pragma unroll
    for (int m = 0; m < 4; m++) {
      int row = m * 16 + lo;
      af[m] = *(const short8*)(As + row * 64 + ((hi ^ (row & 3)) << 4));
    }
    short8 bv = *(const short8*)(Bs + hi * 1024 + (w * 16 + lo) * 16);
#pragma unroll
    for (int m = 0; m < 4; m++)
      acc[m] = __builtin_amdgcn_mfma_f32_16x16x32_bf16(af[m], bv, acc[m], 0, 0, 0);
    __syncthreads();
  }
  int col = nbase + w * 16 + lo;
  int mc = (CMAP == 0) ? col : mapbias(col);
  float bvadd = bias[mc];
#pragma unroll
  for (int m = 0; m < 4; m++) {
#pragma unroll
    for (int r = 0; r < 4; r++) {
      int row = bbase + m * 16 + hi * 4 + r;
      float v = acc[m][r] + bvadd;
      if (RELU) v = fmaxf(v, 0.f);
      if (OUTBF) ((unsigned short*)Out)[(size_t)row * ldo + col] = f2bf(v);
      else       ((float*)Out)[(size_t)row * ldo + col] = v;
    }
  }
}

template <bool RELU, bool OUTF32>
__global__ __launch_bounds__(512, 2)
void layer_fused(const unsigned short* __restrict__ h2bf, const float* __restrict__ W3,
                 const float* __restrict__ b3, const unsigned short* __restrict__ xin,
                 const float* __restrict__ tb, int tbBase, void* __restrict__ Out,
                 int Woff) {
  __shared__ __align__(16) char smem[40960];
  char* As = smem;
  char* Bs = smem + 8192;
  int bx = blockIdx.x, by = blockIdx.y;
  swz_block(bx, by);
  int t = threadIdx.x, lane = t & 63, w = t >> 6;
  int lo = lane & 15, hi = lane >> 4;
  int wm = w >> 2, wo = w & 3;
  int bbase = bx * 128;
  int obase = by * 4;
  int o = obase + wo;
  int colstart = Woff + obase * 128;
  int ar = t >> 2, ach = t & 3;
  const float* bcol0 = W3 + colstart + t;
  f32x4 acc[4][8] = {};
  for (int kb = 0; kb < 1024; kb += 32) {
    uint4 av = *(const uint4*)(h2bf + (size_t)(bbase + ar) * 1024 + kb + ach * 8);
    *(uint4*)(As + ar * 64 + ((ach ^ (ar & 3)) << 4)) = av;
#pragma unroll
    for (int p = 0; p < 2; p++) {
      float fb[16];
      const float* src = bcol0 + (size_t)(kb + p * 16) * 57792;
#pragma unroll
      for (int j = 0; j < 16; j++) fb[j] = src[(size_t)j * 57792];
#pragma unroll
      for (int q = 0; q < 2; q++) {
        uint4 wv;
        wv.x = f2bf(fb[q * 8 + 0]) | ((uint32_t)f2bf(fb[q * 8 + 1]) << 16);
        wv.y = f2bf(fb[q * 8 + 2]) | ((uint32_t)f2bf(fb[q * 8 + 3]) << 16);
        wv.z = f2bf(fb[q * 8 + 4]) | ((uint32_t)f2bf(fb[q * 8 + 5]) << 16);
        wv.w = f2bf(fb[q * 8 + 6]) | ((uint32_t)f2bf(fb[q * 8 + 7]) << 16);
        *(uint4*)(Bs + (p * 2 + q) * 8192 + t * 16) = wv;
      }
    }
    __syncthreads();
    short8 af[4];
#pragma unroll
    for (int m = 0; m < 4; m++) {
      int row = wm * 64 + m * 16 + lo;
      af[m] = *(const short8*)(As + row * 64 + ((hi ^ (row & 3)) << 4));
    }
#pragma unroll
    for (int nf = 0; nf < 8; nf++) {
      short8 bv = *(const short8*)(Bs + hi * 8192 + (wo * 128 + nf * 16 + lo) * 16);
#pragma unroll
      for (int m = 0; m < 4; m++)
        acc[m][nf] = __builtin_amdgcn_mfma_f32_16x16x32_bf16(af[m], bv, acc[m][nf], 0, 0, 0);
    }
    __syncthreads();
  }
#pragma unroll
  for (int pass = 0; pass < 4; pass++) {
    int idx = pass * 512 + t;
    int row = idx >> 4, ch = idx & 15;
    uint4 v = *(const uint4*)(xin + (size_t)(bbase + row) * 128 + ch * 8);
    *(uint4*)(Bs + row * 256 + ch * 16) = v;
  }
  __syncthreads();
  const unsigned short* Xs = (const unsigned short*)Bs;
  float b3g[8];
#pragma unroll
  for (int nf = 0; nf < 8; nf++) b3g[nf] = b3[colstart + wo * 128 + nf * 16 + lo];
  float osum[4][4] = {};
#pragma unroll
  for (int m = 0; m < 4; m++) {
#pragma unroll
    for (int r = 0; r < 4; r++) {
      int brow = wm * 64 + m * 16 + hi * 4 + r;
      float s = 0.f;
#pragma unroll
      for (int nf = 0; nf < 8; nf++) {
        float xv = bf2f(Xs[brow * 128 + nf * 16 + lo]);
        s += (acc[m][nf][r] + b3g[nf]) * xv;
      }
      osum[m][r] = s;
    }
  }
#pragma unroll
  for (int m = 0; m < 4; m++) {
#pragma unroll
    for (int r = 0; r < 4; r++) {
      float v = osum[m][r];
      v += __shfl_xor(v, 1);
      v += __shfl_xor(v, 2);
      v += __shfl_xor(v, 4);
      v += __shfl_xor(v, 8);
      if (lo == 0) {
        int brow = wm * 64 + m * 16 + hi * 4 + r;
        int gb = bbase + brow;
        float y = v + tb[(size_t)gb * 448 + tbBase + o];
        if (RELU) y = fmaxf(y, 0.f);
        if (OUTF32) ((float*)Out)[(size_t)gb * 64 + o] = y;
        else        ((unsigned short*)Out)[(size_t)gb * 128 + o] = f2bf(y);
      }
    }
  }
}

// ---------------------------------------------------------------------------
// softmax over 64 cols; one wave per row
// ---------------------------------------------------------------------------
__global__ void softmax_k(const float* __restrict__ logits, float* __restrict__ out) {
  int t = threadIdx.x, w = t >> 6, lane = t & 63;
  int row = blockIdx.x * 4 + w;
  float v = logits[row * 64 + lane];
  float m = v;
  m = fmaxf(m, __shfl_xor(m, 1));
  m = fmaxf(m, __shfl_xor(m, 2));
  m = fmaxf(m, __shfl_xor(m, 4));
  m = fmaxf(m, __shfl_xor(m, 8));
  m = fmaxf(m, __shfl_xor(m, 16));
  m = fmaxf(m, __shfl_xor(m, 32));
  float e = expf(v - m);
  float s = e;
  s += __shfl_xor(s, 1);
  s += __shfl_xor(s, 2);
  s += __shfl_xor(s, 4);
  s += __shfl_xor(s, 8);
  s += __shfl_xor(s, 16);
  s += __shfl_xor(s, 32);
  out[row * 64 + lane] = e / s;
}

// ---------------------------------------------------------------------------
extern "C" void kernel_launch(void* const* d_in, const int* in_sizes, int n_in,
                              void* d_out, int out_size, void* d_ws, size_t ws_size,
                              hipStream_t stream) {
  (void)in_sizes; (void)n_in; (void)out_size;
  const float* x  = (const float*)d_in[0];
  const float* ow = (const float*)d_in[1];
  const float* W1 = (const float*)d_in[2];
  const float* b1 = (const float*)d_in[3];
  const float* W2 = (const float*)d_in[4];
  const float* b2 = (const float*)d_in[5];
  const float* W3 = (const float*)d_in[6];
  const float* b3 = (const float*)d_in[7];

  char* ws = (char*)d_ws;
  unsigned short* xbf  = (unsigned short*)(ws + 0);          // 2048x128 bf16
  unsigned short* h1bf = (unsigned short*)(ws + 524288);     // 2048x1024 bf16
  unsigned short* h2bf = (unsigned short*)(ws + 4718592);    // 2048x1024 bf16
  float*          tb   = (float*)(ws + 8912896);             // 2048x448 f32
  unsigned short* ht1  = (unsigned short*)(ws + 12582912);   // 2048x128 bf16
  unsigned short* ht2  = (unsigned short*)(ws + 13107200);
  unsigned short* ht3  = (unsigned short*)(ws + 13631488);
  float*       logits  = (float*)(ws + 14155776);            // 2048x64 f32
  unsigned short* W2S  = (unsigned short*)(ws + 14680064);   // 1024x1024 bf16 packed
  unsigned short* W3S  = (unsigned short*)(ws + 16777216);   // 1024x57792 bf16 packed
  const size_t NEED = 16777216 + (size_t)57792 * 1024 * 2;   // 135,135,232 B
  float* out = (float*)d_out;

  prep_x<<<256, 256, 0, stream>>>(x, xbf);
  hyper1_k<<<8192, 256, 0, stream>>>(ow, W1, b1, h1bf);

  if (ws_size >= NEED) {
    pack_b<<<512, 256, 0, stream>>>(W2, W2S, 1024);
    gemm_packed<0, true, true><<<dim3(32, 16), 256, 0, stream>>>(h1bf, W2S, b2, h2bf, 1024, 1024, 1024, 1024);
    pack_b<<<28896, 256, 0, stream>>>(W3, W3S, 57792);
    gemm_packed<1, false, false><<<dim3(32, 7), 256, 0, stream>>>(h2bf, W3S, b3, tb, 1024, 57792, 448, 1024);
    layer_packed<true,  false><<<dim3(16, 64), 512, 0, stream>>>(h2bf, W3S, b3, xbf, tb, 0,   ht1, 0);
    layer_packed<true,  false><<<dim3(16, 64), 512, 0, stream>>>(h2bf, W3S, b3, ht1, tb, 128, ht2, 16512);
    layer_packed<true,  false><<<dim3(16, 64), 512, 0, stream>>>(h2bf, W3S, b3, ht2, tb, 256, ht3, 33024);
    layer_packed<false, true ><<<dim3(16, 32), 512, 0, stream>>>(h2bf, W3S, b3, ht3, tb, 384, logits, 49536);
  } else {
    gemm_small<0, true, true><<<dim3(32, 16), 256, 0, stream>>>(h1bf, W2, b2, h2bf, 1024, 1024, 1024, 1024);
    gemm_small<1, false, false><<<dim3(32, 7), 256, 0, stream>>>(h2bf, W3, b3, tb, 1024, 57792, 448, 1024);
    layer_fused<true,  false><<<dim3(16, 32), 512, 0, stream>>>(h2bf, W3, b3, xbf, tb, 0,   ht1, 0);
    layer_fused<true,  false><<<dim3(16, 32), 512, 0, stream>>>(h2bf, W3, b3, ht1, tb, 128, ht2, 16512);
    layer_fused<true,  false><<<dim3(16, 32), 512, 0, stream>>>(h2bf, W3, b3, ht2, tb, 256, ht3, 33024);
    layer_fused<false, true ><<<dim3(16, 16), 512, 0, stream>>>(h2bf, W3, b3, ht3, tb, 384, logits, 49536);
  }
  softmax_k<<<512, 256, 0, stream>>>(logits, out);
}

// Round 6
// 606.849 us; speedup vs baseline: 1.6014x; 1.0242x over previous
//
#include <hip/hip_runtime.h>
#include <cstdint>
#include <cstddef>

// ---------------------------------------------------------------------------
// Problem constants
//   B=2048, INPUT_DIM=HIDDEN=128, OUT=64, HYPER_H=1024, TOTAL_PARAMS=57792
//   flat col layout: [L1 W 0..16384) [L1 b 16384..16512) [L2 W 16512..32896)
//                    [L2 b 32896..33024) [L3 W 33024..49408) [L3 b 49408..49536)
//                    [L4 W 49536..57728) [L4 b 57728..57792)
// ---------------------------------------------------------------------------

typedef __attribute__((ext_vector_type(8))) short short8;
typedef __attribute__((ext_vector_type(4))) float f32x4;

__device__ __forceinline__ unsigned short f2bf(float f) {
  union { float f; uint32_t u; } c; c.f = f;
  uint32_t u = c.u;
  return (unsigned short)((u + 0x7FFFu + ((u >> 16) & 1u)) >> 16);  // RNE
}
__device__ __forceinline__ float bf2f(unsigned short b) {
  union { uint32_t u; float f; } c; c.u = ((uint32_t)b) << 16;
  return c.f;
}
// tb column j (0..447) -> flat column (bias ranges)
__device__ __forceinline__ int mapbias(int j) {
  if (j < 128) return 16384 + j;
  if (j < 256) return 32768 + j;
  if (j < 384) return 49152 + j;
  return 57344 + j;
}
// XCD-aware bijective block swizzle (requires gridDim.x*gridDim.y % 8 == 0)
__device__ __forceinline__ void swz_block(int& bx, int& by) {
  int gx = gridDim.x;
  int n = gx * gridDim.y;
  int f = by * gx + bx;
  int per = n >> 3;
  int s = (f & 7) * per + (f >> 3);
  bx = s % gx; by = s / gx;
}
// by-major XCD remap: linear%8 == by&7, so each XCD's L2 caches one W3S
// col-slice (4 MB) across all bx re-reads. Requires gridDim.y % 8 == 0.
__device__ __forceinline__ void swz_bymajor(int& bx, int& by) {
  int l = blockIdx.y * gridDim.x + blockIdx.x;
  int xcd = l & 7, rest = l >> 3;
  int gy8 = gridDim.y >> 3;
  by = (rest % gy8) * 8 + xcd;
  bx = rest / gy8;
}
// async global->LDS 16B; dest must be wave-uniform base + lane*16 (linear in t)
__device__ __forceinline__ void gl_lds16(const void* g, void* l) {
  __builtin_amdgcn_global_load_lds(
      (const __attribute__((address_space(1))) void*)g,
      (__attribute__((address_space(3))) void*)l, 16, 0, 0);
}

// ---------------------------------------------------------------------------
// prep: x (2048x128 f32) -> bf16
// ---------------------------------------------------------------------------
__global__ void prep_x(const float* __restrict__ x, unsigned short* __restrict__ xbf) {
  int i = (blockIdx.x * 256 + threadIdx.x) * 4;
  float4 v = *(const float4*)(x + i);
  ushort4 o; o.x = f2bf(v.x); o.y = f2bf(v.y); o.z = f2bf(v.z); o.w = f2bf(v.w);
  *(ushort4*)(xbf + i) = o;
}

// ---------------------------------------------------------------------------
// hyper layer 1: h1 = relu(ow @ W1 + b1) -> bf16   (K=3, trivial)
// ---------------------------------------------------------------------------
__global__ void hyper1_k(const float* __restrict__ ow, const float* __restrict__ W1,
                         const float* __restrict__ b1, unsigned short* __restrict__ h1bf) {
  int idx = blockIdx.x * 256 + threadIdx.x;
  int b = idx >> 10, j = idx & 1023;
  float s = b1[j] + ow[b * 3 + 0] * W1[j]
                  + ow[b * 3 + 1] * W1[1024 + j]
                  + ow[b * 3 + 2] * W1[2048 + j];
  h1bf[idx] = f2bf(fmaxf(s, 0.f));
}

// ---------------------------------------------------------------------------
// pack fp32 [K][N] -> bf16 blocked [(K/32)*4 + kgrp][c][8k]  (one 16B chunk per
// thread; reads coalesced across c, writes contiguous). grid = K*N/8/256.
// ---------------------------------------------------------------------------
__global__ void pack_b(const float* __restrict__ src, unsigned short* __restrict__ dst, int N) {
  int idx = blockIdx.x * 256 + threadIdx.x;     // chunk index = g*N + c
  int c = idx % N;
  int g = idx / N;
  int k0 = (g >> 2) * 32 + (g & 3) * 8;
  const float* s = src + (size_t)k0 * N + c;
  uint4 wv;
  wv.x = f2bf(s[0])            | ((uint32_t)f2bf(s[(size_t)N])     << 16);
  wv.y = f2bf(s[2 * (size_t)N]) | ((uint32_t)f2bf(s[3 * (size_t)N]) << 16);
  wv.z = f2bf(s[4 * (size_t)N]) | ((uint32_t)f2bf(s[5 * (size_t)N]) << 16);
  wv.w = f2bf(s[6 * (size_t)N]) | ((uint32_t)f2bf(s[7 * (size_t)N]) << 16);
  *(uint4*)(dst + (size_t)idx * 8) = wv;
}

// ---------------------------------------------------------------------------
// PACKED small GEMM, 2-phase double-buffered. BM=64 BN=64 BK=32.
// 256 thr / 4 waves; wave w owns cols w*16..+16. Staging via global_load_lds.
// LDS: 2 bufs x (A 4 KB + B 4 KB). A-swz: LDS[row][ch] = A[row][ch^((row>>1)&3)].
// ---------------------------------------------------------------------------
template <int CMAP, bool RELU, bool OUTBF>
__global__ __launch_bounds__(256, 4)
void gemm_packed(const unsigned short* __restrict__ A, const unsigned short* __restrict__ BP,
                 const float* __restrict__ bias, void* __restrict__ Out,
                 int lda, int ldbp, int ldo, int K) {
  __shared__ __align__(16) char smem[16384];
  char* A0 = smem;         char* B0 = smem + 4096;
  char* A1 = smem + 8192;  char* B1 = smem + 12288;
  int bx = blockIdx.x, by = blockIdx.y;
  swz_block(bx, by);
  int t = threadIdx.x, lane = t & 63, w = t >> 6;
  int lo = lane & 15, hi = lane >> 4;
  int bbase = bx * 64, nbase = by * 64;
  int ar = t >> 2, ach = t & 3;
  int bkg = t >> 6, bc = t & 63;
  int bj = nbase + bc;
  int bcol = (CMAP == 0) ? bj : mapbias(bj);

  f32x4 acc[4] = {};

  auto stage = [&](int ks, char* Ab, char* Bb) {
    gl_lds16(A + (size_t)(bbase + ar) * lda + ks * 32 + ((ach ^ ((ar >> 1) & 3)) << 3),
             Ab + t * 16);
    gl_lds16(BP + ((size_t)(ks * 4 + bkg) * ldbp + bcol) * 8, Bb + t * 16);
  };
  auto comp = [&](char* Ab, char* Bb) {
    short8 af[4];
#pragma unroll
    for (int m = 0; m < 4; m++) {
      int row = m * 16 + lo;
      af[m] = *(const short8*)(Ab + row * 64 + ((hi ^ ((row >> 1) & 3)) << 4));
    }
    short8 bv = *(const short8*)(Bb + (hi * 64 + w * 16 + lo) * 16);
#pragma unroll
    for (int m = 0; m < 4; m++)
      acc[m] = __builtin_amdgcn_mfma_f32_16x16x32_bf16(af[m], bv, acc[m], 0, 0, 0);
  };

  int NT = K >> 5;   // even
  stage(0, A0, B0);
  __syncthreads();
  for (int ks = 0; ks < NT; ks += 2) {
    stage(ks + 1, A1, B1);
    comp(A0, B0);
    __syncthreads();
    if (ks + 2 < NT) stage(ks + 2, A0, B0);
    comp(A1, B1);
    __syncthreads();
  }

  int col = nbase + w * 16 + lo;
  int mc = (CMAP == 0) ? col : mapbias(col);
  float bvadd = bias[mc];
#pragma unroll
  for (int m = 0; m < 4; m++) {
#pragma unroll
    for (int r = 0; r < 4; r++) {
      int row = bbase + m * 16 + hi * 4 + r;
      float v = acc[m][r] + bvadd;
      if (RELU) v = fmaxf(v, 0.f);
      if (OUTBF) ((unsigned short*)Out)[(size_t)row * ldo + col] = f2bf(v);
      else       ((float*)Out)[(size_t)row * ldo + col] = v;
    }
  }
}

// ---------------------------------------------------------------------------
// PACKED fused target layer, 2-phase double-buffered. WG = 128 samples x 2
// outputs (256 flat cols). 512 thr / 8 waves = 4M x 2O; wave 32 rows x 128
// cols -> acc[2][8] (64 VGPR). BK=32.
// LDS: 2 bufs x (A 8 KB [128 rows][4 ch] swz ch^((row>>1)&3) + B 16 KB
// [4 kgrp][256 c][16B]) = 48 KB; X tile (32 KB) overlays in epilogue.
// by-major XCD remap keeps each XCD's 4 MB W3S slice in its L2.
// ---------------------------------------------------------------------------
template <bool RELU, bool OUTF32>
__global__ __launch_bounds__(512, 4)
void layer_packed(const unsigned short* __restrict__ h2bf,
                  const unsigned short* __restrict__ W3S,
                  const float* __restrict__ b3,
                  const unsigned short* __restrict__ xin,
                  const float* __restrict__ tb, int tbBase,
                  void* __restrict__ Out, int Woff) {
  __shared__ __align__(16) char smem[49152];
  char* A0 = smem;          char* B0 = smem + 8192;
  char* A1 = smem + 24576;  char* B1 = smem + 32768;
  int bx, by;
  swz_bymajor(bx, by);
  int t = threadIdx.x, lane = t & 63, w = t >> 6;
  int lo = lane & 15, hi = lane >> 4;
  int wm = w >> 1, wo = w & 1;
  int bbase = bx * 128;
  int obase = by * 2;
  int colstart = Woff + obase * 128;   // this WG's 256 flat cols
  int ar = t >> 2, ach = t & 3;

  f32x4 acc[2][8] = {};

  auto stage = [&](int ks, char* Ab, char* Bb) {
    // A: 8 KB, 1 round; LDS[ar][ach] = A[ar][kchunk = ach ^ ((ar>>1)&3)]
    gl_lds16(h2bf + (size_t)(bbase + ar) * 1024 + ks * 32 + ((ach ^ ((ar >> 1) & 3)) << 3),
             Ab + t * 16);
    // B: 16 KB, 2 rounds; [kgrp][c][16B], packed groups k-contiguous
#pragma unroll
    for (int r = 0; r < 2; r++) {
      int idx = r * 512 + t;
      int kgrp = idx >> 8, c = idx & 255;
      gl_lds16(W3S + ((size_t)(ks * 4 + kgrp) * 57792 + colstart + c) * 8,
               Bb + idx * 16);
    }
  };
  auto comp = [&](char* Ab, char* Bb) {
    short8 af[2];
#pragma unroll
    for (int m = 0; m < 2; m++) {
      int row = wm * 32 + m * 16 + lo;
      af[m] = *(const short8*)(Ab + row * 64 + ((hi ^ ((row >> 1) & 3)) << 4));
    }
#pragma unroll
    for (int nf = 0; nf < 8; nf++) {
      short8 bv = *(const short8*)(Bb + (hi * 256 + wo * 128 + nf * 16 + lo) * 16);
      acc[0][nf] = __builtin_amdgcn_mfma_f32_16x16x32_bf16(af[0], bv, acc[0][nf], 0, 0, 0);
      acc[1][nf] = __builtin_amdgcn_mfma_f32_16x16x32_bf16(af[1], bv, acc[1][nf], 0, 0, 0);
    }
  };

  stage(0, A0, B0);
  __syncthreads();
  for (int ks = 0; ks < 32; ks += 2) {
    stage(ks + 1, A1, B1);       // prefetch next K-step into other buffer
    comp(A0, B0);                // compute current
    __syncthreads();             // drain + WAR protect
    if (ks + 2 < 32) stage(ks + 2, A0, B0);
    comp(A1, B1);
    __syncthreads();
  }

  // stage xin tile (128x128 bf16 = 32 KB) over smem
#pragma unroll
  for (int r = 0; r < 4; r++) {
    int idx = r * 512 + t;
    int row = idx >> 4, ch = idx & 15;
    gl_lds16(xin + (size_t)(bbase + row) * 128 + ch * 8, smem + idx * 16);
  }
  __syncthreads();
  const unsigned short* Xs = (const unsigned short*)smem;

  int o = obase + wo;
  float b3g[8];
#pragma unroll
  for (int nf = 0; nf < 8; nf++) b3g[nf] = b3[colstart + wo * 128 + nf * 16 + lo];

#pragma unroll
  for (int m = 0; m < 2; m++) {
#pragma unroll
    for (int r = 0; r < 4; r++) {
      int brow = wm * 32 + m * 16 + hi * 4 + r;
      float s = 0.f;
#pragma unroll
      for (int nf = 0; nf < 8; nf++) {
        float xv = bf2f(Xs[brow * 128 + nf * 16 + lo]);
        s += (acc[m][nf][r] + b3g[nf]) * xv;
      }
      s += __shfl_xor(s, 1);
      s += __shfl_xor(s, 2);
      s += __shfl_xor(s, 4);
      s += __shfl_xor(s, 8);
      if (lo == 0) {
        int gb = bbase + brow;
        float y = s + tb[(size_t)gb * 448 + tbBase + o];
        if (RELU) y = fmaxf(y, 0.f);
        if (OUTF32) ((float*)Out)[(size_t)gb * 64 + o] = y;
        else        ((unsigned short*)Out)[(size_t)gb * 128 + o] = f2bf(y);
      }
    }
  }
}

// ---------------------------------------------------------------------------
// FALLBACK path (round-1 kernels, used when ws_size can't hold packed W3)
// ---------------------------------------------------------------------------
template <int CMAP, bool RELU, bool OUTBF>
__global__ __launch_bounds__(256, 2)
void gemm_small(const unsigned short* __restrict__ A, const float* __restrict__ Bsrc,
                const float* __restrict__ bias, void* __restrict__ Out,
                int lda, int ldb, int ldo, int K) {
  __shared__ __align__(16) char smem[8192];
  char* As = smem;
  char* Bs = smem + 4096;
  int bx = blockIdx.x, by = blockIdx.y;
  swz_block(bx, by);
  int t = threadIdx.x, lane = t & 63, w = t >> 6;
  int lo = lane & 15, hi = lane >> 4;
  int bbase = bx * 64, nbase = by * 64;
  int bn = t & 63, bp = t >> 6;
  int bj = nbase + bn;
  int bcol = (CMAP == 0) ? bj : mapbias(bj);
  int ar = t >> 2, ach = t & 3;
  f32x4 acc[4] = {};
  for (int kb = 0; kb < K; kb += 32) {
    uint4 av = *(const uint4*)(A + (size_t)(bbase + ar) * lda + kb + ach * 8);
    *(uint4*)(As + ar * 64 + ((ach ^ (ar & 3)) << 4)) = av;
    float fb[8];
    const float* src = Bsrc + (size_t)(kb + bp * 8) * ldb + bcol;
#pragma unroll
    for (int j = 0; j < 8; j++) fb[j] = src[(size_t)j * ldb];
    uint4 wv;
    wv.x = f2bf(fb[0]) | ((uint32_t)f2bf(fb[1]) << 16);
    wv.y = f2bf(fb[2]) | ((uint32_t)f2bf(fb[3]) << 16);
    wv.z = f2bf(fb[4]) | ((uint32_t)f2bf(fb[5]) << 16);
    wv.w = f2bf(fb[6]) | ((uint32_t)f2bf(fb[7]) << 16);
    *(uint4*)(Bs + bp * 1024 + bn * 16) = wv;
    __syncthreads();
    short8 af[4];
#pragma unroll
    for (int m = 0; m < 4; m++) {
      int row = m * 16 + lo;
      af[m] = *(const short8*)(As + row * 64 + ((hi ^ (row & 3)) << 4));
    }
    short8 bv = *(const short8*)(Bs + hi * 1024 + (w * 16 + lo) * 16);
#pragma unroll
    for (int m = 0; m < 4; m++)
      acc[m] = __builtin_amdgcn_mfma_f32_16x16x32_bf16(af[m], bv, acc[m], 0, 0, 0);
    __syncthreads();
  }
  int col = nbase + w * 16 + lo;
  int mc = (CMAP == 0) ? col : mapbias(col);
  float bvadd = bias[mc];
#pragma unroll
  for (int m = 0; m < 4; m++) {
#pragma unroll
    for (int r = 0; r < 4; r++) {
      int row = bbase + m * 16 + hi * 4 + r;
      float v = acc[m][r] + bvadd;
      if (RELU) v = fmaxf(v, 0.f);
      if (OUTBF) ((unsigned short*)Out)[(size_t)row * ldo + col] = f2bf(v);
      else       ((float*)Out)[(size_t)row * ldo + col] = v;
    }
  }
}

template <bool RELU, bool OUTF32>
__global__ __launch_bounds__(512, 2)
void layer_fused(const unsigned short* __restrict__ h2bf, const float* __restrict__ W3,
                 const float* __restrict__ b3, const unsigned short* __restrict__ xin,
                 const float* __restrict__ tb, int tbBase, void* __restrict__ Out,
                 int Woff) {
  __shared__ __align__(16) char smem[40960];
  char* As = smem;
  char* Bs = smem + 8192;
  int bx = blockIdx.x, by = blockIdx.y;
  swz_block(bx, by);
  int t = threadIdx.x, lane = t & 63, w = t >> 6;
  int lo = lane & 15, hi = lane >> 4;
  int wm = w >> 2, wo = w & 3;
  int bbase = bx * 128;
  int obase = by * 4;
  int o = obase + wo;
  int colstart = Woff + obase * 128;
  int ar = t >> 2, ach = t & 3;
  const float* bcol0 = W3 + colstart + t;
  f32x4 acc[4][8] = {};
  for (int kb = 0; kb < 1024; kb += 32) {
    uint4 av = *(const uint4*)(h2bf + (size_t)(bbase + ar) * 1024 + kb + ach * 8);
    *(uint4*)(As + ar * 64 + ((ach ^ (ar & 3)) << 4)) = av;
#pragma unroll
    for (int p = 0; p < 2; p++) {
      float fb[16];
      const float* src = bcol0 + (size_t)(kb + p * 16) * 57792;
#pragma unroll
      for (int j = 0; j < 16; j++) fb[j] = src[(size_t)j * 57792];
#pragma unroll
      for (int q = 0; q < 2; q++) {
        uint4 wv;
        wv.x = f2bf(fb[q * 8 + 0]) | ((uint32_t)f2bf(fb[q * 8 + 1]) << 16);
        wv.y = f2bf(fb[q * 8 + 2]) | ((uint32_t)f2bf(fb[q * 8 + 3]) << 16);
        wv.z = f2bf(fb[q * 8 + 4]) | ((uint32_t)f2bf(fb[q * 8 + 5]) << 16);
        wv.w = f2bf(fb[q * 8 + 6]) | ((uint32_t)f2bf(fb[q * 8 + 7]) << 16);
        *(uint4*)(Bs + (p * 2 + q) * 8192 + t * 16) = wv;
      }
    }
    __syncthreads();
    short8 af[4];
#pragma unroll
    for (int m = 0; m < 4; m++) {
      int row = wm * 64 + m * 16 + lo;
      af[m] = *(const short8*)(As + row * 64 + ((hi ^ (row & 3)) << 4));
    }
#pragma unroll
    for (int nf = 0; nf < 8; nf++) {
      short8 bv = *(const short8*)(Bs + hi * 8192 + (wo * 128 + nf * 16 + lo) * 16);
#pragma unroll
      for (int m = 0; m < 4; m++)
        acc[m][nf] = __builtin_amdgcn_mfma_f32_16x16x32_bf16(af[m], bv, acc[m][nf], 0, 0, 0);
    }
    __syncthreads();
  }
#pragma unroll
  for (int pass = 0; pass < 4; pass++) {
    int idx = pass * 512 + t;
    int row = idx >> 4, ch = idx & 15;
    uint4 v = *(const uint4*)(xin + (size_t)(bbase + row) * 128 + ch * 8);
    *(uint4*)(Bs + row * 256 + ch * 16) = v;
  }
  __syncthreads();
  const unsigned short* Xs = (const unsigned short*)Bs;
  float b3g[8];
#pragma unroll
  for (int nf = 0; nf < 8; nf++) b3g[nf] = b3[colstart + wo * 128 + nf * 16 + lo];
  float osum[4][4] = {};
#pragma unroll
  for (int m = 0; m < 4; m++) {
#pragma unroll
    for (int r = 0; r < 4; r++) {
      int brow = wm * 64 + m * 16 + hi * 4 + r;
      float s = 0.f;
#pragma unroll
      for (int nf = 0; nf < 8; nf++) {
        float xv = bf2f(Xs[brow * 128 + nf * 16 + lo]);
        s += (acc[m][nf][r] + b3g[nf]) * xv;
      }
      osum[m][r] = s;
    }
  }
#pragma unroll
  for (int m = 0; m < 4; m++) {
#pragma unroll
    for (int r = 0; r < 4; r++) {
      float v = osum[m][r];
      v += __shfl_xor(v, 1);
      v += __shfl_xor(v, 2);
      v += __shfl_xor(v, 4);
      v += __shfl_xor(v, 8);
      if (lo == 0) {
        int brow = wm * 64 + m * 16 + hi * 4 + r;
        int gb = bbase + brow;
        float y = v + tb[(size_t)gb * 448 + tbBase + o];
        if (RELU) y = fmaxf(y, 0.f);
        if (OUTF32) ((float*)Out)[(size_t)gb * 64 + o] = y;
        else        ((unsigned short*)Out)[(size_t)gb * 128 + o] = f2bf(y);
      }
    }
  }
}

// ---------------------------------------------------------------------------
// softmax over 64 cols; one wave per row
// ---------------------------------------------------------------------------
__global__ void softmax_k(const float* __restrict__ logits, float* __restrict__ out) {
  int t = threadIdx.x, w = t >> 6, lane = t & 63;
  int row = blockIdx.x * 4 + w;
  float v = logits[row * 64 + lane];
  float m = v;
  m = fmaxf(m, __shfl_xor(m, 1));
  m = fmaxf(m, __shfl_xor(m, 2));
  m = fmaxf(m, __shfl_xor(m, 4));
  m = fmaxf(m, __shfl_xor(m, 8));
  m = fmaxf(m, __shfl_xor(m, 16));
  m = fmaxf(m, __shfl_xor(m, 32));
  float e = expf(v - m);
  float s = e;
  s += __shfl_xor(s, 1);
  s += __shfl_xor(s, 2);
  s += __shfl_xor(s, 4);
  s += __shfl_xor(s, 8);
  s += __shfl_xor(s, 16);
  s += __shfl_xor(s, 32);
  out[row * 64 + lane] = e / s;
}

// ---------------------------------------------------------------------------
extern "C" void kernel_launch(void* const* d_in, const int* in_sizes, int n_in,
                              void* d_out, int out_size, void* d_ws, size_t ws_size,
                              hipStream_t stream) {
  (void)in_sizes; (void)n_in; (void)out_size;
  const float* x  = (const float*)d_in[0];
  const float* ow = (const float*)d_in[1];
  const float* W1 = (const float*)d_in[2];
  const float* b1 = (const float*)d_in[3];
  const float* W2 = (const float*)d_in[4];
  const float* b2 = (const float*)d_in[5];
  const float* W3 = (const float*)d_in[6];
  const float* b3 = (const float*)d_in[7];

  char* ws = (char*)d_ws;
  unsigned short* xbf  = (unsigned short*)(ws + 0);          // 2048x128 bf16
  unsigned short* h1bf = (unsigned short*)(ws + 524288);     // 2048x1024 bf16
  unsigned short* h2bf = (unsigned short*)(ws + 4718592);    // 2048x1024 bf16
  float*          tb   = (float*)(ws + 8912896);             // 2048x448 f32
  unsigned short* ht1  = (unsigned short*)(ws + 12582912);   // 2048x128 bf16
  unsigned short* ht2  = (unsigned short*)(ws + 13107200);
  unsigned short* ht3  = (unsigned short*)(ws + 13631488);
  float*       logits  = (float*)(ws + 14155776);            // 2048x64 f32
  unsigned short* W2S  = (unsigned short*)(ws + 14680064);   // 1024x1024 bf16 packed
  unsigned short* W3S  = (unsigned short*)(ws + 16777216);   // 1024x57792 bf16 packed
  const size_t NEED = 16777216 + (size_t)57792 * 1024 * 2;   // 135,135,232 B
  float* out = (float*)d_out;

  prep_x<<<256, 256, 0, stream>>>(x, xbf);
  hyper1_k<<<8192, 256, 0, stream>>>(ow, W1, b1, h1bf);

  if (ws_size >= NEED) {
    pack_b<<<512, 256, 0, stream>>>(W2, W2S, 1024);
    gemm_packed<0, true, true><<<dim3(32, 16), 256, 0, stream>>>(h1bf, W2S, b2, h2bf, 1024, 1024, 1024, 1024);
    pack_b<<<28896, 256, 0, stream>>>(W3, W3S, 57792);
    gemm_packed<1, false, false><<<dim3(32, 7), 256, 0, stream>>>(h2bf, W3S, b3, tb, 1024, 57792, 448, 1024);
    layer_packed<true,  false><<<dim3(16, 64), 512, 0, stream>>>(h2bf, W3S, b3, xbf, tb, 0,   ht1, 0);
    layer_packed<true,  false><<<dim3(16, 64), 512, 0, stream>>>(h2bf, W3S, b3, ht1, tb, 128, ht2, 16512);
    layer_packed<true,  false><<<dim3(16, 64), 512, 0, stream>>>(h2bf, W3S, b3, ht2, tb, 256, ht3, 33024);
    layer_packed<false, true ><<<dim3(16, 32), 512, 0, stream>>>(h2bf, W3S, b3, ht3, tb, 384, logits, 49536);
  } else {
    gemm_small<0, true, true><<<dim3(32, 16), 256, 0, stream>>>(h1bf, W2, b2, h2bf, 1024, 1024, 1024, 1024);
    gemm_small<1, false, false><<<dim3(32, 7), 256, 0, stream>>>(h2bf, W3, b3, tb, 1024, 57792, 448, 1024);
    layer_fused<true,  false><<<dim3(16, 32), 512, 0, stream>>>(h2bf, W3, b3, xbf, tb, 0,   ht1, 0);
    layer_fused<true,  false><<<dim3(16, 32), 512, 0, stream>>>(h2bf, W3, b3, ht1, tb, 128, ht2, 16512);
    layer_fused<true,  false><<<dim3(16, 32), 512, 0, stream>>>(h2bf, W3, b3, ht2, tb, 256, ht3, 33024);
    layer_fused<false, true ><<<dim3(16, 16), 512, 0, stream>>>(h2bf, W3, b3, ht3, tb, 384, logits, 49536);
  }
  softmax_k<<<512, 256, 0, stream>>>(logits, out);
}